// Round 13
// baseline (560.957 us; speedup 1.0000x reference)
//
#include <hip/hip_runtime.h>
#include <cstdint>
#include <cstddef>

// ---------------------------------------------------------------------------
// Net_25950192402497: 2-layer MLP-message GNN + link-prediction head.
// Identity: segment_sum(concat(x_i,x_j,ef)@W + b) over dst
//   = deg*(h@Wi + b) + (gather-sum h[src])@Wj + (gather-sum ef)@We
// R13: XCD-sliced gather. h split into 4 column slices (3.2MB each, fits a
// 4MB per-XCD L2). Blocks read the REAL XCD id via s_getreg(HW_REG_XCC_ID)
// [learn_hip m09], prefer slice xcc&3 via per-slice atomic tickets, then
// WORK-STEAL other slices -> correctness independent of XCD mapping (G16).
// R12's gather was latency-bound on ~600cyc L3 hits (FETCH=8 XCDs x full
// 12.8MB table); slicing turns those into ~200cyc L2 hits.
// ---------------------------------------------------------------------------

typedef __attribute__((ext_vector_type(8))) short short8;
typedef __attribute__((ext_vector_type(4))) float float4v;

__device__ __forceinline__ ushort f2b(float f) {
    uint u = __float_as_uint(f);
    u = u + 0x7fff + ((u >> 16) & 1);          // round-to-nearest-even
    return (ushort)(u >> 16);
}
__device__ __forceinline__ float b2f(ushort h) {
    return __uint_as_float(((uint)h) << 16);
}
__device__ __forceinline__ uint pack2(float a, float b) {
    return (uint)f2b(a) | ((uint)f2b(b) << 16);
}
__device__ __forceinline__ int xcc_id() {
    int x;
    asm volatile("s_getreg_b32 %0, hwreg(20, 0, 4)" : "=s"(x));  // HW_REG_XCC_ID
    return x;
}

#define F_MSG     1   // X = [deg*A | B | EF | 0] in k-space (Kp=320)
#define F_RELU    2
#define F_DEGBIAS 4
#define F_OUTB    8   // write bf16 output [row][128]
#define F_IN32    16  // A is fp32, convert during staging
#define F_HEAD    32  // no row output; emit z[row] = {za0,za1,zb0,zb1}

#define XS_STRIDE 72  // 144 B rows: max 2-way bank aliasing (free), 16B aligned

// MFMA GEMM (R9/R12 form): act( X[r,0:Kp] @ W[Kp,128] + bias ).
__launch_bounds__(256, 2)
__global__ void gemm_mfma(const ushort* __restrict__ A, const ushort* __restrict__ B,
                          const ushort* __restrict__ EF, const float* __restrict__ A32,
                          const float* __restrict__ DEG, const ushort* __restrict__ Wt,
                          const float* __restrict__ bias, ushort* __restrict__ outB,
                          const float* __restrict__ lpW, float* __restrict__ z,
                          int M, int Kp, int flags)
{
    __shared__ ushort xs[128 * XS_STRIDE];   // 18 KB
    __shared__ ushort ws[128 * XS_STRIDE];   // 18 KB
    const int tid  = threadIdx.x;
    const int lane = tid & 63;
    const int wave = tid >> 6;
    const int row0 = blockIdx.x << 7;

    float4v acc[2][8];
#pragma unroll
    for (int m = 0; m < 2; ++m)
#pragma unroll
        for (int t = 0; t < 8; ++t) acc[m][t] = (float4v){0.f, 0.f, 0.f, 0.f};

    const int arow0 = (wave << 5) + (lane & 15);
    const int koff  = (lane >> 4) << 3;
    const int bcol  = lane & 15;

    for (int kt = 0; kt < Kp; kt += 64) {
        __syncthreads();
        for (int idx = tid; idx < 128 * 8; idx += 256) {
            const int n = idx >> 3;
            const int g = idx & 7;
            const uint4 v = *(const uint4*)&Wt[(size_t)n * Kp + kt + (g << 3)];
            *(uint4*)&ws[n * XS_STRIDE + (g << 3)] = v;
        }
        if (flags & F_MSG) {
            for (int idx = tid; idx < 128 * 8; idx += 256) {
                const int r  = idx >> 3;
                const int g  = idx & 7;
                const int gr = row0 + r;
                const int kk = kt + (g << 3);
                uint4 v = make_uint4(0, 0, 0, 0);
                if (gr < M) {
                    if (kk < 128) {                       // deg * A
                        uint4 a = *(const uint4*)&A[((size_t)gr << 7) + kk];
                        const float d = DEG[gr];
                        uint* p = (uint*)&a;
#pragma unroll
                        for (int q = 0; q < 4; ++q)
                            p[q] = pack2(b2f((ushort)(p[q] & 0xffff)) * d,
                                         b2f((ushort)(p[q] >> 16)) * d);
                        v = a;
                    } else if (kk < 256) {                // B
                        v = *(const uint4*)&B[((size_t)gr << 7) + kk - 128];
                    } else if (kk < 272) {                // EF
                        v = *(const uint4*)&EF[((size_t)gr << 4) + kk - 256];
                    }
                }
                *(uint4*)&xs[r * XS_STRIDE + (g << 3)] = v;
            }
        } else if (flags & F_IN32) {
            for (int idx = tid; idx < 128 * 8; idx += 256) {
                const int r  = idx >> 3;
                const int g  = idx & 7;
                const int gr = row0 + r;
                uint4 v = make_uint4(0, 0, 0, 0);
                if (gr < M) {
                    const float4 f0 = *(const float4*)&A32[((size_t)gr << 7) + kt + (g << 3)];
                    const float4 f1 = *(const float4*)&A32[((size_t)gr << 7) + kt + (g << 3) + 4];
                    v.x = pack2(f0.x, f0.y); v.y = pack2(f0.z, f0.w);
                    v.z = pack2(f1.x, f1.y); v.w = pack2(f1.z, f1.w);
                }
                *(uint4*)&xs[r * XS_STRIDE + (g << 3)] = v;
            }
        } else {
            for (int idx = tid; idx < 128 * 8; idx += 256) {
                const int r  = idx >> 3;
                const int g  = idx & 7;
                const int gr = row0 + r;
                uint4 v = make_uint4(0, 0, 0, 0);
                if (gr < M) v = *(const uint4*)&A[((size_t)gr << 7) + kt + (g << 3)];
                *(uint4*)&xs[r * XS_STRIDE + (g << 3)] = v;
            }
        }
        __syncthreads();
#pragma unroll
        for (int s = 0; s < 64; s += 32) {
            const short8 a0 = *(const short8*)&xs[arow0 * XS_STRIDE + s + koff];
            const short8 a1 = *(const short8*)&xs[(arow0 + 16) * XS_STRIDE + s + koff];
#pragma unroll
            for (int t = 0; t < 8; ++t) {
                const short8 bf = *(const short8*)&ws[((t << 4) + bcol) * XS_STRIDE + s + koff];
                acc[0][t] = __builtin_amdgcn_mfma_f32_16x16x32_bf16(a0, bf, acc[0][t], 0, 0, 0);
                acc[1][t] = __builtin_amdgcn_mfma_f32_16x16x32_bf16(a1, bf, acc[1][t], 0, 0, 0);
            }
        }
    }

    float bcv[8];
#pragma unroll
    for (int t = 0; t < 8; ++t) bcv[t] = bias[(t << 4) + bcol];

    if (flags & F_HEAD) {
        const float2* lw = (const float2*)lpW;
        float2 wa[8], wb[8];
#pragma unroll
        for (int t = 0; t < 8; ++t) {
            const int col = (t << 4) + bcol;
            wa[t] = lw[col];
            wb[t] = lw[128 + col];
        }
#pragma unroll
        for (int m = 0; m < 2; ++m) {
            const int rbase = row0 + (wave << 5) + (m << 4) + ((lane >> 4) << 2);
#pragma unroll
            for (int r = 0; r < 4; ++r) {
                const int row = rbase + r;
                const float d = (row < M) ? DEG[row] : 0.f;
                float za0 = 0.f, za1 = 0.f, zb0 = 0.f, zb1 = 0.f;
#pragma unroll
                for (int t = 0; t < 8; ++t) {
                    const float v = acc[m][t][r] + d * bcv[t];
                    za0 += v * wa[t].x; za1 += v * wa[t].y;
                    zb0 += v * wb[t].x; zb1 += v * wb[t].y;
                }
#pragma unroll
                for (int mk = 8; mk > 0; mk >>= 1) {
                    za0 += __shfl_xor(za0, mk);
                    za1 += __shfl_xor(za1, mk);
                    zb0 += __shfl_xor(zb0, mk);
                    zb1 += __shfl_xor(zb1, mk);
                }
                if (bcol == 0 && row < M)
                    *(float4*)&z[(size_t)row * 4] = make_float4(za0, za1, zb0, zb1);
            }
        }
    } else {
#pragma unroll
        for (int m = 0; m < 2; ++m) {
            const int rbase = row0 + (wave << 5) + (m << 4) + ((lane >> 4) << 2);
#pragma unroll
            for (int t = 0; t < 8; ++t) {
                const int col = (t << 4) + bcol;
#pragma unroll
                for (int r = 0; r < 4; ++r) {
                    const int row = rbase + r;
                    if (row >= M) continue;
                    float v = acc[m][t][r];
                    v += (flags & F_DEGBIAS) ? DEG[row] * bcv[t] : bcv[t];
                    if (flags & F_RELU) v = fmaxf(v, 0.f);
                    outB[((size_t)row << 7) + col] = f2b(v);
                }
            }
        }
    }
}

// ---- prep: zero counts + tickets + convert weights ----
__launch_bounds__(256)
__global__ void prep(const float* __restrict__ c1pW, const float* __restrict__ c2pW,
                     const float* __restrict__ c1mW, const float* __restrict__ c2mW,
                     ushort* __restrict__ wtp1, ushort* __restrict__ wtp2,
                     ushort* __restrict__ wtm1, ushort* __restrict__ wtm2,
                     int* __restrict__ counts, int* __restrict__ tickets, int N)
{
    const int gtid = blockIdx.x * 256 + threadIdx.x;
    const int gstr = gridDim.x * 256;
    if (gtid < 8) tickets[gtid] = 0;
    for (int i = gtid; i < N; i += gstr) counts[i] = 0;
    for (int idx = gtid; idx < 128 * 128; idx += gstr) {
        const int n = idx >> 7, k = idx & 127;
        wtp1[idx] = f2b(c1pW[(size_t)k * 128 + n]);
        wtp2[idx] = f2b(c2pW[(size_t)k * 128 + n]);
    }
    for (int idx = gtid; idx < 128 * 320; idx += gstr) {
        const int n = idx / 320, k = idx - n * 320;
        wtm1[idx] = (k < 272) ? f2b(c1mW[(size_t)k * 128 + n]) : (ushort)0;
        wtm2[idx] = (k < 272) ? f2b(c2mW[(size_t)k * 128 + n]) : (ushort)0;
    }
}

__launch_bounds__(256)
__global__ void hist_kernel(const int* __restrict__ ei, int* __restrict__ counts, int E)
{
    const int e = blockIdx.x * 256 + threadIdx.x;
    if (e < E) atomicAdd(&counts[ei[E + e]], 1);
}

__launch_bounds__(256)
__global__ void scan_phase1(const int* __restrict__ counts, int* __restrict__ rowstart,
                            int* __restrict__ blocksums, int N)
{
    __shared__ int sdata[256];
    const int t = threadIdx.x;
    const int i = blockIdx.x * 256 + t;
    const int v = (i < N) ? counts[i] : 0;
    sdata[t] = v;
    __syncthreads();
    for (int off = 1; off < 256; off <<= 1) {
        const int add = (t >= off) ? sdata[t - off] : 0;
        __syncthreads();
        sdata[t] += add;
        __syncthreads();
    }
    if (i < N) rowstart[i] = sdata[t] - v;
    if (t == 255) blocksums[blockIdx.x] = sdata[255];
}

__launch_bounds__(256)
__global__ void scan_phase23(const int* __restrict__ counts, const int* __restrict__ bs,
                             int* __restrict__ rowstart, int* __restrict__ cursor,
                             float* __restrict__ degf, int N, int E)
{
    __shared__ int sdata[256];
    const int t = threadIdx.x;
    const int vb = blockIdx.x;
    int part = 0;
    for (int j = t; j < vb; j += 256) part += bs[j];
    sdata[t] = part;
    __syncthreads();
    for (int s = 128; s > 0; s >>= 1) {
        if (t < s) sdata[t] += sdata[t + s];
        __syncthreads();
    }
    const int off = sdata[0];
    const int i = vb * 256 + t;
    if (i < N) {
        const int rs = rowstart[i] + off;
        rowstart[i] = rs;
        cursor[i]   = rs;
        degf[i]     = (float)counts[i];
    }
    if (vb == 0 && t == 0) rowstart[N] = E;
}

__launch_bounds__(256)
__global__ void build_elist(const int* __restrict__ ei, int* __restrict__ cursor,
                            int2* __restrict__ elist, int E)
{
    const int e = blockIdx.x * 256 + threadIdx.x;
    if (e >= E) return;
    const int d = ei[E + e];
    const int pos = atomicAdd(&cursor[d], 1);
    elist[pos] = make_int2(ei[e], e);
}

// gather, XCD-sliced: 4 column slices of 32 cols (64B). Per (slice, chunk of
// 64 nodes): 4 lanes/node, uint4 (16B)/lane, unroll-4. Slice chosen by real
// XCC_ID preference + work stealing over per-slice tickets.
__launch_bounds__(256)
__global__ void gather(const int2* __restrict__ elist, const int* __restrict__ rowstart,
                       const ushort* __restrict__ h, ushort* __restrict__ agg,
                       const float* __restrict__ ef, ushort* __restrict__ aggef,
                       int* __restrict__ tickets, int tbase, int N, int doEf)
{
    const int tid = threadIdx.x;
    if (doEf) {
        const int nvb = (N + 15) / 16;
        const int lane16 = tid & 15;
        for (int vb = blockIdx.x; vb < nvb; vb += gridDim.x) {
            const int node = vb * 16 + (tid >> 4);
            if (node >= N) continue;
            const int beg = rowstart[node];
            const int end = rowstart[node + 1];
            float acc = 0.f;
            for (int k = beg; k < end; ++k)
                acc += ef[((size_t)elist[k].y << 4) + lane16];
            aggef[((size_t)node << 4) + lane16] = f2b(acc);
        }
    }

    __shared__ int s_chunk;
    const int nchunks = (N + 63) / 64;
    const int pref = xcc_id() & 3;
    const int grp = tid >> 2;              // node-in-chunk 0..63
    const int l   = tid & 3;               // 4 lanes per node
    const int co  = l << 3;                // ushort offset within slice (8 ush=16B)

    for (int si = 0; si < 4; ++si) {
        const int slice = (pref + si) & 3;
        const int sbase = slice << 5;      // 32 cols per slice
        while (true) {
            __syncthreads();
            if (tid == 0) s_chunk = atomicAdd(&tickets[tbase + slice], 1);
            __syncthreads();
            const int c = s_chunk;
            if (c >= nchunks) break;
            const int node = c * 64 + grp;
            if (node >= N) continue;
            const int beg = rowstart[node];
            const int end = rowstart[node + 1];
            float a0 = 0.f, a1 = 0.f, a2 = 0.f, a3 = 0.f,
                  a4 = 0.f, a5 = 0.f, a6 = 0.f, a7 = 0.f;
            int k = beg;
            for (; k + 3 < end; k += 4) {
                uint4 v[4];
#pragma unroll
                for (int j = 0; j < 4; ++j) {
                    const int s = elist[k + j].x;
                    v[j] = *(const uint4*)&h[((size_t)s << 7) + sbase + co];
                }
#pragma unroll
                for (int j = 0; j < 4; ++j) {
                    a0 += b2f((ushort)(v[j].x & 0xffff));
                    a1 += b2f((ushort)(v[j].x >> 16));
                    a2 += b2f((ushort)(v[j].y & 0xffff));
                    a3 += b2f((ushort)(v[j].y >> 16));
                    a4 += b2f((ushort)(v[j].z & 0xffff));
                    a5 += b2f((ushort)(v[j].z >> 16));
                    a6 += b2f((ushort)(v[j].w & 0xffff));
                    a7 += b2f((ushort)(v[j].w >> 16));
                }
            }
            for (; k < end; ++k) {
                const uint4 v = *(const uint4*)&h[((size_t)elist[k].x << 7) + sbase + co];
                a0 += b2f((ushort)(v.x & 0xffff));
                a1 += b2f((ushort)(v.x >> 16));
                a2 += b2f((ushort)(v.y & 0xffff));
                a3 += b2f((ushort)(v.y >> 16));
                a4 += b2f((ushort)(v.z & 0xffff));
                a5 += b2f((ushort)(v.z >> 16));
                a6 += b2f((ushort)(v.w & 0xffff));
                a7 += b2f((ushort)(v.w >> 16));
            }
            uint4 o;
            o.x = pack2(a0, a1);
            o.y = pack2(a2, a3);
            o.z = pack2(a4, a5);
            o.w = pack2(a6, a7);
            *(uint4*)&agg[((size_t)node << 7) + sbase + co] = o;
        }
    }
}

// head: out[q] = z[a].topdot + z[b].botdot + lpb
__launch_bounds__(256)
__global__ void head_kernel(const float4* __restrict__ z, const int* __restrict__ eli,
                            const float* __restrict__ lpb, float* __restrict__ out, int Q)
{
    const int q = blockIdx.x * 256 + threadIdx.x;
    if (q >= Q) return;
    const int a = eli[q];
    const int b = eli[Q + q];
    const float4 za = z[a];
    const float4 zb = z[b];
    float2 o = make_float2(za.x + zb.z + lpb[0], za.y + zb.w + lpb[1]);
    *(float2*)&out[(size_t)q * 2] = o;
}

extern "C" void kernel_launch(void* const* d_in, const int* in_sizes, int n_in,
                              void* d_out, int out_size, void* d_ws, size_t ws_size,
                              hipStream_t stream)
{
    const float* nf   = (const float*)d_in[0];
    const int*   ei   = (const int*)d_in[1];
    const float* ef   = (const float*)d_in[2];
    const int*   eli  = (const int*)d_in[3];
    const float* c1pW = (const float*)d_in[4];
    const float* c1pb = (const float*)d_in[5];
    const float* c1mW = (const float*)d_in[6];
    const float* c1mb = (const float*)d_in[7];
    const float* c2pW = (const float*)d_in[8];
    const float* c2pb = (const float*)d_in[9];
    const float* c2mW = (const float*)d_in[10];
    const float* c2mb = (const float*)d_in[11];
    const float* lpW  = (const float*)d_in[12];
    const float* lpb  = (const float*)d_in[13];
    float* out = (float*)d_out;

    const int N = in_sizes[0] / 128;
    const int E = in_sizes[1] / 2;
    const int Q = in_sizes[3] / 2;

    // ---- workspace layout ----
    float* DEG = (float*)d_ws;                 // N
    float* z   = DEG + N;                      // N*4 fp32 (head projections)
    int* counts    = (int*)(z + (size_t)N * 4);// N
    int* rowstart  = counts + N;               // N+1
    int* cursor    = rowstart + N + 1;         // N
    int* blocksums = cursor + N;               // 1024 pad (scan uses ~196)
    int* tickets   = blocksums + 512;          // 8 ints inside the pad
    uintptr_t ep8 = (uintptr_t)(blocksums + 1024);
    ep8 = (ep8 + 7) & ~(uintptr_t)7;
    int2* elist = (int2*)ep8;                  // E int2 (src, edge id)
    uintptr_t up = (uintptr_t)(elist + E);
    up = (up + 15) & ~(uintptr_t)15;
    ushort* h_bf   = (ushort*)up;              // N*128
    ushort* agg_bf = h_bf   + (size_t)N * 128; // N*128
    ushort* x1_bf  = agg_bf + (size_t)N * 128; // N*128
    ushort* ef_bf  = x1_bf  + (size_t)N * 128; // N*16
    ushort* wtp1   = ef_bf  + (size_t)N * 16;  // 128*128
    ushort* wtm1   = wtp1 + 128 * 128;         // 128*320
    ushort* wtp2   = wtm1 + 128 * 320;         // 128*128
    ushort* wtm2   = wtp2 + 128 * 128;         // 128*320

    const int gemmGrid = (N + 127) / 128;
    const int eGrid    = (E + 255) / 256;
    const int nGrid    = (N + 255) / 256;
    const int gGrid    = 2048;
    const int headGrid = (Q + 255) / 256;

    // ---- prep + CSR build ----
    prep<<<nGrid, 256, 0, stream>>>(c1pW, c2pW, c1mW, c2mW, wtp1, wtp2, wtm1, wtm2,
                                    counts, tickets, N);
    hist_kernel<<<eGrid, 256, 0, stream>>>(ei, counts, E);
    scan_phase1<<<nGrid, 256, 0, stream>>>(counts, rowstart, blocksums, N);
    scan_phase23<<<nGrid, 256, 0, stream>>>(counts, blocksums, rowstart, cursor, DEG, N, E);
    build_elist<<<eGrid, 256, 0, stream>>>(ei, cursor, elist, E);

    // ---- conv1 ----
    gemm_mfma<<<gemmGrid, 256, 0, stream>>>(nullptr, nullptr, nullptr, nf, DEG, wtp1,
                                            c1pb, h_bf, nullptr, nullptr, N, 128,
                                            F_RELU | F_OUTB | F_IN32);
    gather<<<gGrid, 256, 0, stream>>>(elist, rowstart, h_bf, agg_bf, ef, ef_bf,
                                      tickets, 0, N, 1);
    gemm_mfma<<<gemmGrid, 256, 0, stream>>>(h_bf, agg_bf, ef_bf, nullptr, DEG, wtm1,
                                            c1mb, x1_bf, nullptr, nullptr, N, 320,
                                            F_MSG | F_RELU | F_DEGBIAS | F_OUTB);

    // ---- conv2 ----
    gemm_mfma<<<gemmGrid, 256, 0, stream>>>(x1_bf, nullptr, nullptr, nullptr, DEG, wtp2,
                                            c2pb, h_bf, nullptr, nullptr, N, 128,
                                            F_RELU | F_OUTB);
    gather<<<gGrid, 256, 0, stream>>>(elist, rowstart, h_bf, agg_bf, nullptr, nullptr,
                                      tickets, 4, N, 0);
    gemm_mfma<<<gemmGrid, 256, 0, stream>>>(h_bf, agg_bf, ef_bf, nullptr, DEG, wtm2,
                                            c2mb, nullptr, lpW, z, N, 320,
                                            F_MSG | F_DEGBIAS | F_HEAD);

    // ---- head ----
    head_kernel<<<headGrid, 256, 0, stream>>>((const float4*)z, eli, lpb, out, Q);
}